// Round 5
// baseline (1654.323 us; speedup 1.0000x reference)
//
#include <hip/hip_runtime.h>
#include <hip/hip_bf16.h>
#include <cstdint>
#include <cstddef>

// Problem constants
#define BSZ  256
#define TDIM 128
#define DDIM 256
#define HIDN 256
#define G3   768   // 3*HID

using bf16x8 = __attribute__((ext_vector_type(8))) short;   // 8 bf16 in 4 VGPRs
using f32x4  = __attribute__((ext_vector_type(4))) float;   // MFMA accumulator

__device__ __forceinline__ unsigned short f2bf(float f) {
  union { float f; unsigned u; } x; x.f = f;
  unsigned r = x.u + 0x7FFFu + ((x.u >> 16) & 1u);   // RNE, inputs are sane
  return (unsigned short)(r >> 16);
}
__device__ __forceinline__ float sigm(float x) {
  return __builtin_amdgcn_rcpf(1.f + __expf(-x));
}
__device__ __forceinline__ float tanh_f(float x) {
  float e = __expf(2.f * x);
  return 1.f - 2.f * __builtin_amdgcn_rcpf(e + 1.f);
}
__device__ __forceinline__ float gelu_f(float x) {
  return 0.5f * x * (1.f + erff(x * 0.70710678118654752f));
}

// ---------------- fp32 -> bf16 convert ----------------
__global__ __launch_bounds__(256) void cvt_bf16(const float* __restrict__ src,
                                                unsigned short* __restrict__ dst, int n4) {
  int i = blockIdx.x * 256 + threadIdx.x;
  if (i >= n4) return;
  float4 v = ((const float4*)src)[i];
  ushort4 o;
  o.x = f2bf(v.x); o.y = f2bf(v.y); o.z = f2bf(v.z); o.w = f2bf(v.w);
  ((ushort4*)dst)[i] = o;
}

// ---------------- async global->LDS staging ----------------
#if defined(__has_builtin)
#if __has_builtin(__builtin_amdgcn_global_load_lds)
#define HAVE_GLL 1
#endif
#endif
#ifndef HAVE_GLL
#define HAVE_GLL 0
#endif

__device__ __forceinline__ void stage16(const unsigned short* gp,
                                        unsigned short* lbase, int lane) {
#if HAVE_GLL
  __builtin_amdgcn_global_load_lds((const __attribute__((address_space(1))) void*)gp,
                                   (__attribute__((address_space(3))) void*)lbase, 16, 0, 0);
#else
  *(bf16x8*)(lbase + lane * 8) = *(const bf16x8*)gp;
#endif
}

// ---------------- bf16 MFMA GEMM: C[m,n] = sum_k A[m,k]*B[n,k] (+bias, +gelu) ----------------
// 128x128 tile, BK=32, 256 threads (4 waves, each 64x64), chunk-major LDS (conflict-free b128).
__global__ __launch_bounds__(256) void gemm_bf16(
    const unsigned short* __restrict__ A, int lda,
    const unsigned short* __restrict__ B, int ldb,
    const float* __restrict__ bias,
    float* __restrict__ Cf, unsigned short* __restrict__ Cbf,
    int K, int ldc, int do_gelu)
{
  __shared__ unsigned short As[4096], Bs[4096];   // 8KB each: [chunk c][row r] 16B slots
  const int tid = threadIdx.x;
  const int w = tid >> 6, lane = tid & 63;
  const int m16 = lane & 15, quad = lane >> 4;
  const int m0 = blockIdx.y * 128, n0 = blockIdx.x * 128;
  const int wm = w >> 1, wn = w & 1;

  const f32x4 z4 = {0.f, 0.f, 0.f, 0.f};
  f32x4 acc[4][4];
#pragma unroll
  for (int i = 0; i < 4; ++i)
#pragma unroll
    for (int j = 0; j < 4; ++j) acc[i][j] = z4;

  const int nk = K >> 5;
  for (int kk = 0; kk < nk; ++kk) {
#pragma unroll
    for (int i = 0; i < 2; ++i) {
      const int r = i * 64 + lane;                 // row within tile
      stage16(A + (size_t)(m0 + r) * lda + kk * 32 + w * 8, &As[w * 1024 + i * 512], lane);
      stage16(B + (size_t)(n0 + r) * ldb + kk * 32 + w * 8, &Bs[w * 1024 + i * 512], lane);
    }
    __syncthreads();
    bf16x8 af[4], bfr[4];
#pragma unroll
    for (int i = 0; i < 4; ++i) {
      af[i]  = *(const bf16x8*)&As[quad * 1024 + (wm * 64 + i * 16 + m16) * 8];
      bfr[i] = *(const bf16x8*)&Bs[quad * 1024 + (wn * 64 + i * 16 + m16) * 8];
    }
#pragma unroll
    for (int i = 0; i < 4; ++i)
#pragma unroll
      for (int j = 0; j < 4; ++j)
        acc[i][j] = __builtin_amdgcn_mfma_f32_16x16x32_bf16(af[i], bfr[j], acc[i][j], 0, 0, 0);
    __syncthreads();
  }

#pragma unroll
  for (int i = 0; i < 4; ++i) {
    const int row0 = m0 + wm * 64 + i * 16 + quad * 4;
#pragma unroll
    for (int j = 0; j < 4; ++j) {
      const int col = n0 + wn * 64 + j * 16 + m16;
#pragma unroll
      for (int rg = 0; rg < 4; ++rg) {
        float v = acc[i][j][rg];
        if (bias) v += bias[col];
        if (do_gelu) v = gelu_f(v);
        const size_t off = (size_t)(row0 + rg) * ldc + col;
        if (Cf)  Cf[off] = v;
        if (Cbf) Cbf[off] = f2bf(v);
      }
    }
  }
}

// ---------------- GRU recurrence (one layer) ----------------
// OCCUPANCY variant of the proven r0 structure. 16 blocks x 16 batch rows; 1024 threads =
// 16 waves (4 waves/SIMD, double r0's 2), wave w owns hidden cols [16w, 16w+16).
// Per-wave register state halves vs r0 (wreg r,z = 64 regs, giv 12, acc 12) so 16 waves
// fit the 128-reg/wave budget -> latency chains (Wn L2 stream, gi loads, LDS reads,
// barrier drain) are covered by co-resident waves instead of exposed.
// Step internals are EXACTLY r0's proven ordering: gi loads at top, Wn streamed from L2
// inside the MFMA loop, stores at end, full __syncthreads (vmcnt drain keeps the in-order
// VMEM queue empty at each step start - r3/r4 proved removing it hurts).
__global__ __launch_bounds__(1024, 4) void gru_rec(
    const float* __restrict__ gi,            // (BS*T, 768), rows b*T+t (bih already added)
    const unsigned short* __restrict__ Whh,  // (768, 256) bf16
    const float* __restrict__ bhh,           // (768,)
    float* __restrict__ Hf,                  // (BS,T,HID) fp32 or nullptr
    unsigned short* __restrict__ Hbf)        // (BS,T,HID) bf16
{
  __shared__ unsigned short hs[2][16 * 256]; // [buf][row r][chunk c at (c^r)]
  const int tid = threadIdx.x;
  const int w = tid >> 6, lane = tid & 63;
  const int m16 = lane & 15, quad = lane >> 4;
  const int b0 = blockIdx.x * 16;
  const int colw = w * 16;                   // 16 cols per wave

  for (int i = tid; i < 16 * 256; i += 1024) hs[0][i] = 0;   // h0 = 0

  // r,z-gate weight B-fragments resident in registers: 16 x bf16x8 = 64 regs
  bf16x8 wreg[2][8];
#pragma unroll
  for (int g = 0; g < 2; ++g)
#pragma unroll
    for (int kk = 0; kk < 8; ++kk)
      wreg[g][kk] = *(const bf16x8*)&Whh[(size_t)(g * 256 + colw + m16) * 256
                                          + kk * 32 + quad * 8];

  // n-gate streamed: per-lane base pointer (kk*64B fits in imm offset)
  const unsigned short* Wn0 = &Whh[(size_t)(512 + colw + m16) * 256 + quad * 8];

  float bb[3];
#pragma unroll
  for (int g = 0; g < 3; ++g) bb[g] = bhh[g * 256 + colw + m16];

  float hreg[4] = {};                        // h for rows quad*4+rg, col colw+m16
  const f32x4 z4 = {0.f, 0.f, 0.f, 0.f};
  __syncthreads();

  for (int t = 0; t < TDIM; ++t) {
    const unsigned short* hsr = hs[t & 1];
    unsigned short*       hsw = hs[(t + 1) & 1];

    // gi loads issued early (independent of MFMA); consumed at gate time (end of step)
    float giv[3][4];
#pragma unroll
    for (int g = 0; g < 3; ++g)
#pragma unroll
      for (int rg = 0; rg < 4; ++rg)
        giv[g][rg] = gi[(size_t)((b0 + quad * 4 + rg) * TDIM + t) * G3
                        + g * 256 + colw + m16];

    f32x4 acc0 = z4, acc1 = z4, acc2 = z4;

#pragma unroll
    for (int kk = 0; kk < 8; ++kk) {
      const int c = kk * 4 + quad;
      const bf16x8 a  = *(const bf16x8*)&hsr[m16 * 256 + ((c ^ m16) * 8)];
      const bf16x8 bn = *(const bf16x8*)&Wn0[kk * 32];    // L2-resident stream
      acc0 = __builtin_amdgcn_mfma_f32_16x16x32_bf16(a, wreg[0][kk], acc0, 0, 0, 0);
      acc1 = __builtin_amdgcn_mfma_f32_16x16x32_bf16(a, wreg[1][kk], acc1, 0, 0, 0);
      acc2 = __builtin_amdgcn_mfma_f32_16x16x32_bf16(a, bn, acc2, 0, 0, 0);
    }

#pragma unroll
    for (int rg = 0; rg < 4; ++rg) {
      const float ghr = acc0[rg] + bb[0];
      const float ghz = acc1[rg] + bb[1];
      const float ghn = acc2[rg] + bb[2];
      const float r = sigm(giv[0][rg] + ghr);
      const float z = sigm(giv[1][rg] + ghz);
      const float n = tanh_f(giv[2][rg] + r * ghn);
      float h = hreg[rg];
      h = n + z * (h - n);                   // (1-z)*n + z*h
      hreg[rg] = h;
      const int row = quad * 4 + rg;
      const int col = colw + m16;
      const unsigned short hb = f2bf(h);
      hsw[row * 256 + (((col >> 3) ^ row) * 8) + (col & 7)] = hb;
      const size_t gidx = (size_t)((b0 + row) * TDIM + t) * HIDN + col;
      Hbf[gidx] = hb;
      if (Hf) Hf[gidx] = h;
    }
    __syncthreads();   // h_{t+1} buffer complete (and VMEM queue drained) before next step
  }
}

// ---------------- contrastive loss + alpha ----------------
// grid (127, 8); block 256 = 4 waves; wave handles 8 batch rows serially.
__global__ __launch_bounds__(256) void loss_k(
    const float* __restrict__ WC, const float* __restrict__ P,
    const int* __restrict__ neg, float* __restrict__ alpha, float* __restrict__ loss)
{
  const int t = blockIdx.x;                       // 0..126
  const int w = threadIdx.x >> 6, lane = threadIdx.x & 63;
  __shared__ float wls[4];
  float lsum = 0.f;
#pragma unroll 1
  for (int bi = 0; bi < 8; ++bi) {
    const int b = blockIdx.y * 32 + w * 8 + bi;
    const float4 wc4 = *(const float4*)&WC[(size_t)(b * TDIM + t) * DDIM + lane * 4];
    float s[16];
    {
      const float4 p4 = *(const float4*)&P[(size_t)(b * TDIM + t + 1) * DDIM + lane * 4];
      s[0] = wc4.x * p4.x + wc4.y * p4.y + wc4.z * p4.z + wc4.w * p4.w;
    }
#pragma unroll
    for (int n = 0; n < 15; ++n) {
      const int rb = neg[(t * 15 + n) * 256 + b];
      const float4 p4 = *(const float4*)&P[(size_t)(rb * TDIM + t + 1) * DDIM + lane * 4];
      s[n + 1] = wc4.x * p4.x + wc4.y * p4.y + wc4.z * p4.z + wc4.w * p4.w;
    }
#pragma unroll
    for (int n = 0; n < 16; ++n) {
      float v = s[n];
#pragma unroll
      for (int off = 32; off > 0; off >>= 1) v += __shfl_xor(v, off);
      s[n] = v * (1.f / 256.f);                   // mean over D
    }
    float mx = s[0];
#pragma unroll
    for (int n = 1; n < 16; ++n) mx = fmaxf(mx, s[n]);
    float se = 0.f;
#pragma unroll
    for (int n = 0; n < 16; ++n) se += __expf(s[n] - mx);
    lsum -= (s[0] - mx - __logf(se));             // -pos_ce
    if (t == TDIM - 2 && lane == 0) alpha[b] = s[0];   // alpha == sp[:,126]
  }
  if (lane == 0) wls[w] = lsum;
  __syncthreads();
  if (threadIdx.x == 0)
    atomicAdd(loss, (wls[0] + wls[1] + wls[2] + wls[3]) * (1.f / 256.f));
}

// ---------------- y = gelu(H[:,-1]@Wp1^T) @ Wp2^T (second half) ----------------
__global__ __launch_bounds__(256) void y_k(const float* __restrict__ Yh,
                                           const float* __restrict__ Wp2,
                                           float* __restrict__ y) {
  const int w = threadIdx.x >> 6, lane = threadIdx.x & 63;
  const int b = blockIdx.x * 4 + w;
  const float4 a = *(const float4*)&Yh[(size_t)b * 256 + lane * 4];
  const float4 q = *(const float4*)&Wp2[lane * 4];
  float s = a.x * q.x + a.y * q.y + a.z * q.z + a.w * q.w;
#pragma unroll
  for (int off = 32; off > 0; off >>= 1) s += __shfl_xor(s, off);
  if (lane == 0) y[b] = s;
}

// ---------------- launch ----------------
extern "C" void kernel_launch(void* const* d_in, const int* in_sizes, int n_in,
                              void* d_out, int out_size, void* d_ws, size_t ws_size,
                              hipStream_t stream) {
  (void)in_sizes; (void)n_in; (void)out_size; (void)ws_size;
  const float* P    = (const float*)d_in[0];
  const float* bih0 = (const float*)d_in[3];
  const float* bhh0 = (const float*)d_in[4];
  const float* bih1 = (const float*)d_in[7];
  const float* bhh1 = (const float*)d_in[8];

  char* ws = (char*)d_ws;
  float*          gi   = (float*)(ws + 0);                       // 100663296 B
  unsigned short* Xbf  = (unsigned short*)(ws + 100663296);      // 16777216 B (H1bf then Hbf)
  unsigned short* Pbf  = (unsigned short*)(ws + 117440512);      // 16777216 B (Pbf then G1bf)
  float*          WC   = (float*)(ws + 134217728);               // 33554432 B
  unsigned short* wb   = (unsigned short*)(ws + 167772160);      // 2097152 B of bf16 weights
  unsigned short* wih0b = wb;
  unsigned short* whh0b = wb + 196608;
  unsigned short* wih1b = wb + 393216;
  unsigned short* whh1b = wb + 589824;
  unsigned short* wbW   = wb + 786432;
  unsigned short* wp1b  = wb + 851968;
  unsigned short* wr1b  = wb + 917504;
  unsigned short* wr2b  = wb + 983040;
  float*          Yh   = (float*)(ws + 169869312);               // 262144 B

  float* out  = (float*)d_out;
  float* Hout = out;                  // 8388608
  float* Yout = out + 8388608;        // 256
  float* Rout = out + 8388864;        // 8388608
  float* Aout = out + 16777472;       // 256
  float* Lout = out + 16777728;       // 1

  cvt_bf16<<<8192, 256, 0, stream>>>(P, Pbf, 2097152);
  cvt_bf16<<<192, 256, 0, stream>>>((const float*)d_in[1], wih0b, 49152);
  cvt_bf16<<<192, 256, 0, stream>>>((const float*)d_in[2], whh0b, 49152);
  cvt_bf16<<<192, 256, 0, stream>>>((const float*)d_in[5], wih1b, 49152);
  cvt_bf16<<<192, 256, 0, stream>>>((const float*)d_in[6], whh1b, 49152);
  cvt_bf16<<<64, 256, 0, stream>>>((const float*)d_in[9],  wbW,  16384);
  cvt_bf16<<<64, 256, 0, stream>>>((const float*)d_in[10], wp1b, 16384);
  cvt_bf16<<<64, 256, 0, stream>>>((const float*)d_in[12], wr1b, 16384);
  cvt_bf16<<<64, 256, 0, stream>>>((const float*)d_in[13], wr2b, 16384);

  dim3 thr(256);
  // gi0 = Pbf @ Wih0^T + bih0
  gemm_bf16<<<dim3(6, 256), thr, 0, stream>>>(Pbf, 256, wih0b, 256, bih0, gi, nullptr, 256, 768, 0);
  // layer 0 recurrence -> H1bf
  gru_rec<<<16, 1024, 0, stream>>>(gi, whh0b, bhh0, nullptr, Xbf);
  // gi1 = H1bf @ Wih1^T + bih1
  gemm_bf16<<<dim3(6, 256), thr, 0, stream>>>(Xbf, 256, wih1b, 256, bih1, gi, nullptr, 256, 768, 0);
  // layer 1 recurrence -> H (fp32 out) + Hbf
  gru_rec<<<16, 1024, 0, stream>>>(gi, whh1b, bhh1, Hout, Xbf);
  // WCfull = H @ W^T
  gemm_bf16<<<dim3(2, 256), thr, 0, stream>>>(Xbf, 256, wbW, 256, nullptr, WC, nullptr, 256, 256, 0);
  // G1 = gelu(H @ Wr1^T) (bf16 only, reuse Pbf)
  gemm_bf16<<<dim3(2, 256), thr, 0, stream>>>(Xbf, 256, wr1b, 256, nullptr, nullptr, Pbf, 256, 256, 1);
  // R = G1 @ Wr2^T
  gemm_bf16<<<dim3(2, 256), thr, 0, stream>>>(Pbf, 256, wr2b, 256, nullptr, Rout, nullptr, 256, 256, 0);
  // Yh = gelu(H[:,127,:] @ Wp1^T)  (A rows strided by T*HID)
  gemm_bf16<<<dim3(2, 2), thr, 0, stream>>>(Xbf + 127 * 256, 32768, wp1b, 256, nullptr, Yh, nullptr, 256, 256, 1);
  y_k<<<64, 256, 0, stream>>>(Yh, (const float*)d_in[11], Yout);

  hipMemsetAsync(Lout, 0, 4, stream);
  loss_k<<<dim3(127, 8), thr, 0, stream>>>(WC, P, (const int*)d_in[14], Aout, Lout);
}

// Round 7
// 902.876 us; speedup vs baseline: 1.8323x; 1.8323x over previous
//
#include <hip/hip_runtime.h>
#include <hip/hip_bf16.h>
#include <cstdint>
#include <cstddef>

// Problem constants
#define BSZ  256
#define TDIM 128
#define DDIM 256
#define HIDN 256
#define G3   768   // 3*HID

using bf16x8 = __attribute__((ext_vector_type(8))) short;   // 8 bf16 in 4 VGPRs
using f32x4  = __attribute__((ext_vector_type(4))) float;   // MFMA accumulator

__device__ __forceinline__ unsigned short f2bf(float f) {
  union { float f; unsigned u; } x; x.f = f;
  unsigned r = x.u + 0x7FFFu + ((x.u >> 16) & 1u);   // RNE, inputs are sane
  return (unsigned short)(r >> 16);
}
__device__ __forceinline__ float sigm(float x) {
  return __builtin_amdgcn_rcpf(1.f + __expf(-x));
}
__device__ __forceinline__ float tanh_f(float x) {
  float e = __expf(2.f * x);
  return 1.f - 2.f * __builtin_amdgcn_rcpf(e + 1.f);
}
__device__ __forceinline__ float gelu_f(float x) {
  return 0.5f * x * (1.f + erff(x * 0.70710678118654752f));
}

// ---------------- fp32 -> bf16 convert ----------------
__global__ __launch_bounds__(256) void cvt_bf16(const float* __restrict__ src,
                                                unsigned short* __restrict__ dst, int n4) {
  int i = blockIdx.x * 256 + threadIdx.x;
  if (i >= n4) return;
  float4 v = ((const float4*)src)[i];
  ushort4 o;
  o.x = f2bf(v.x); o.y = f2bf(v.y); o.z = f2bf(v.z); o.w = f2bf(v.w);
  ((ushort4*)dst)[i] = o;
}

// ---------------- n-gate weight repack into MFMA-fragment order ----------------
// slot(kk, w, t2, lane) <- Whh[(512 + w*32 + t2*16 + (lane&15)) * 256 + kk*32 + (lane>>4)*8]
// Fragment-order layout so the LDS copy is linear and per-step LDS reads are
// lane-contiguous 1KB wave reads (conflict-free ds_read_b128, zero address math).
__global__ __launch_bounds__(256) void wn_pack(const unsigned short* __restrict__ whh,
                                               unsigned short* __restrict__ wnp) {
  const int i = blockIdx.x * 256 + threadIdx.x;      // 8192 slots of 8 shorts
  const int lane = i & 63, t2 = (i >> 6) & 1, w = (i >> 7) & 7, kk = i >> 10;
  const int m16 = lane & 15, quad = lane >> 4;
  *(bf16x8*)&wnp[(size_t)i * 8] =
      *(const bf16x8*)&whh[(size_t)(512 + w * 32 + t2 * 16 + m16) * 256 + kk * 32 + quad * 8];
}

// ---------------- async global->LDS staging ----------------
#if defined(__has_builtin)
#if __has_builtin(__builtin_amdgcn_global_load_lds)
#define HAVE_GLL 1
#endif
#endif
#ifndef HAVE_GLL
#define HAVE_GLL 0
#endif

__device__ __forceinline__ void stage16(const unsigned short* gp,
                                        unsigned short* lbase, int lane) {
#if HAVE_GLL
  __builtin_amdgcn_global_load_lds((const __attribute__((address_space(1))) void*)gp,
                                   (__attribute__((address_space(3))) void*)lbase, 16, 0, 0);
#else
  *(bf16x8*)(lbase + lane * 8) = *(const bf16x8*)gp;
#endif
}

// ---------------- bf16 MFMA GEMM: C[m,n] = sum_k A[m,k]*B[n,k] (+bias, +gelu) ----------------
// 128x128 tile, BK=32, 256 threads (4 waves, each 64x64), chunk-major LDS (conflict-free b128).
__global__ __launch_bounds__(256) void gemm_bf16(
    const unsigned short* __restrict__ A, int lda,
    const unsigned short* __restrict__ B, int ldb,
    const float* __restrict__ bias,
    float* __restrict__ Cf, unsigned short* __restrict__ Cbf,
    int K, int ldc, int do_gelu)
{
  __shared__ unsigned short As[4096], Bs[4096];   // 8KB each: [chunk c][row r] 16B slots
  const int tid = threadIdx.x;
  const int w = tid >> 6, lane = tid & 63;
  const int m16 = lane & 15, quad = lane >> 4;
  const int m0 = blockIdx.y * 128, n0 = blockIdx.x * 128;
  const int wm = w >> 1, wn = w & 1;

  const f32x4 z4 = {0.f, 0.f, 0.f, 0.f};
  f32x4 acc[4][4];
#pragma unroll
  for (int i = 0; i < 4; ++i)
#pragma unroll
    for (int j = 0; j < 4; ++j) acc[i][j] = z4;

  const int nk = K >> 5;
  for (int kk = 0; kk < nk; ++kk) {
#pragma unroll
    for (int i = 0; i < 2; ++i) {
      const int r = i * 64 + lane;                 // row within tile
      stage16(A + (size_t)(m0 + r) * lda + kk * 32 + w * 8, &As[w * 1024 + i * 512], lane);
      stage16(B + (size_t)(n0 + r) * ldb + kk * 32 + w * 8, &Bs[w * 1024 + i * 512], lane);
    }
    __syncthreads();
    bf16x8 af[4], bfr[4];
#pragma unroll
    for (int i = 0; i < 4; ++i) {
      af[i]  = *(const bf16x8*)&As[quad * 1024 + (wm * 64 + i * 16 + m16) * 8];
      bfr[i] = *(const bf16x8*)&Bs[quad * 1024 + (wn * 64 + i * 16 + m16) * 8];
    }
#pragma unroll
    for (int i = 0; i < 4; ++i)
#pragma unroll
      for (int j = 0; j < 4; ++j)
        acc[i][j] = __builtin_amdgcn_mfma_f32_16x16x32_bf16(af[i], bfr[j], acc[i][j], 0, 0, 0);
    __syncthreads();
  }

#pragma unroll
  for (int i = 0; i < 4; ++i) {
    const int row0 = m0 + wm * 64 + i * 16 + quad * 4;
#pragma unroll
    for (int j = 0; j < 4; ++j) {
      const int col = n0 + wn * 64 + j * 16 + m16;
#pragma unroll
      for (int rg = 0; rg < 4; ++rg) {
        float v = acc[i][j][rg];
        if (bias) v += bias[col];
        if (do_gelu) v = gelu_f(v);
        const size_t off = (size_t)(row0 + rg) * ldc + col;
        if (Cf)  Cf[off] = v;
        if (Cbf) Cbf[off] = f2bf(v);
      }
    }
  }
}

// ---------------- GRU recurrence (one layer) ----------------
// r0-proven structure (435us) with ONE change: the n-gate weight slice lives in LDS
// (staged ONCE at kernel start via global_load_lds from the fragment-order repack).
// Mechanism: vmcnt retirement is in-order (FIFO). In r0 the per-step Wn loads sat BEHIND
// the 24 gi L3/HBM loads in the queue, so every Wn wait in the MFMA loop ate gi latency;
// the 128KB/step L2 Wn stream (100% L1-miss) added its own pipelined latency. With Wn in
// LDS, the per-step VMEM queue holds ONLY gi loads (issued at top, consumed ~1500cy later
// at gate time -> fully hidden, nothing younger ever waits on them) and stores (drained at
// the barrier, ~200cy, proven cheap in r0). The MFMA loop is pure LDS+MFMA.
// Everything else identical to r0: 16 blocks x 16 rows, 8 waves x 32 cols, wreg r,z in
// registers, hs XOR-swizzled dbuf, gi at top, stores at end, full __syncthreads.
__global__ __launch_bounds__(512, 2) void gru_rec(
    const float* __restrict__ gi,            // (BS*T, 768), rows b*T+t (bih already added)
    const unsigned short* __restrict__ Whh,  // (768, 256) bf16
    const unsigned short* __restrict__ Wnp,  // n-gate fragment-order repack (131072 B)
    const float* __restrict__ bhh,           // (768,)
    float* __restrict__ Hf,                  // (BS,T,HID) fp32 or nullptr
    unsigned short* __restrict__ Hbf)        // (BS,T,HID) bf16
{
  __shared__ unsigned short hs[2][16 * 256]; // [buf][row r][chunk c at (c^r)]  16KB
  __shared__ unsigned short wn[65536];       // n-gate weights, fragment order  128KB
  const int tid = threadIdx.x;
  const int w = tid >> 6, lane = tid & 63;
  const int m16 = lane & 15, quad = lane >> 4;
  const int b0 = blockIdx.x * 16;
  const int colw = w * 32;

  for (int i = tid; i < 16 * 256; i += 512) hs[0][i] = 0;   // h0 = 0 (buf1 fully overwritten at t=0)

  // stage the n-gate fragment-order slice into LDS once (16 x 8KB, async)
#pragma unroll
  for (int it = 0; it < 16; ++it)
    stage16(Wnp + (size_t)(it * 512 + w * 64 + lane) * 8,
            &wn[(it * 512 + w * 64) * 8], lane);

  // r,z-gate weight B-fragments resident in registers: 32 x bf16x8 = 128 regs
  bf16x8 wreg[2][2][8];
#pragma unroll
  for (int g = 0; g < 2; ++g)
#pragma unroll
    for (int t2 = 0; t2 < 2; ++t2)
#pragma unroll
      for (int kk = 0; kk < 8; ++kk)
        wreg[g][t2][kk] = *(const bf16x8*)&Whh[(size_t)(g * 256 + colw + t2 * 16 + m16) * 256
                                                + kk * 32 + quad * 8];

  float bb[3][2];
#pragma unroll
  for (int g = 0; g < 3; ++g)
#pragma unroll
    for (int t2 = 0; t2 < 2; ++t2)
      bb[g][t2] = bhh[g * 256 + colw + t2 * 16 + m16];

  // per-lane LDS base for the n-gate fragment reads (byte offsets kk*16384 + t2*1024)
  const unsigned short* wnT = &wn[(w * 128 + lane) * 8];

  float hreg[2][4] = {};                     // h for (col tile t2, row quad*4+rg)
  const f32x4 z4 = {0.f, 0.f, 0.f, 0.f};
  __syncthreads();                           // hs zeros + wn staging complete (vmcnt drain)

  for (int t = 0; t < TDIM; ++t) {
    const unsigned short* hsr = hs[t & 1];
    unsigned short*       hsw = hs[(t + 1) & 1];

    // gi loads issued early; the ONLY VMEM loads in the queue -> no FIFO poison,
    // consumed at gate time (~1500cy later) -> latency fully hidden
    float giv[3][2][4];
#pragma unroll
    for (int g = 0; g < 3; ++g)
#pragma unroll
      for (int t2 = 0; t2 < 2; ++t2)
#pragma unroll
        for (int rg = 0; rg < 4; ++rg)
          giv[g][t2][rg] = gi[(size_t)((b0 + quad * 4 + rg) * TDIM + t) * G3
                              + g * 256 + colw + t2 * 16 + m16];

    f32x4 acc[3][2];
#pragma unroll
    for (int g = 0; g < 3; ++g) { acc[g][0] = z4; acc[g][1] = z4; }

    // pure LDS + MFMA inner loop (no vmcnt waits at all)
#pragma unroll
    for (int kk = 0; kk < 8; ++kk) {
      const int c = kk * 4 + quad;
      const bf16x8 a   = *(const bf16x8*)&hsr[m16 * 256 + ((c ^ m16) * 8)];
      const bf16x8 bn0 = *(const bf16x8*)&wnT[kk * 8192];
      const bf16x8 bn1 = *(const bf16x8*)&wnT[kk * 8192 + 512];
      acc[0][0] = __builtin_amdgcn_mfma_f32_16x16x32_bf16(a, wreg[0][0][kk], acc[0][0], 0, 0, 0);
      acc[0][1] = __builtin_amdgcn_mfma_f32_16x16x32_bf16(a, wreg[0][1][kk], acc[0][1], 0, 0, 0);
      acc[1][0] = __builtin_amdgcn_mfma_f32_16x16x32_bf16(a, wreg[1][0][kk], acc[1][0], 0, 0, 0);
      acc[1][1] = __builtin_amdgcn_mfma_f32_16x16x32_bf16(a, wreg[1][1][kk], acc[1][1], 0, 0, 0);
      acc[2][0] = __builtin_amdgcn_mfma_f32_16x16x32_bf16(a, bn0, acc[2][0], 0, 0, 0);
      acc[2][1] = __builtin_amdgcn_mfma_f32_16x16x32_bf16(a, bn1, acc[2][1], 0, 0, 0);
    }

#pragma unroll
    for (int rg = 0; rg < 4; ++rg) {
      float hh[2];
#pragma unroll
      for (int t2 = 0; t2 < 2; ++t2) {
        const float ghr = acc[0][t2][rg] + bb[0][t2];
        const float ghz = acc[1][t2][rg] + bb[1][t2];
        const float ghn = acc[2][t2][rg] + bb[2][t2];
        const float r = sigm(giv[0][t2][rg] + ghr);
        const float z = sigm(giv[1][t2][rg] + ghz);
        const float n = tanh_f(giv[2][t2][rg] + r * ghn);
        float h = hreg[t2][rg];
        h = n + z * (h - n);                 // (1-z)*n + z*h
        hreg[t2][rg] = h;
        hh[t2] = h;
      }
      const unsigned short hb0 = f2bf(hh[0]);
      const unsigned short hb1 = f2bf(hh[1]);
      const int row = quad * 4 + rg;
      const int col0 = colw + m16, col1 = col0 + 16;
      hsw[row * 256 + (((col0 >> 3) ^ row) * 8) + (col0 & 7)] = hb0;
      hsw[row * 256 + (((col1 >> 3) ^ row) * 8) + (col1 & 7)] = hb1;
      const size_t gidx = (size_t)((b0 + row) * TDIM + t) * HIDN + col0;
      Hbf[gidx]      = hb0;
      Hbf[gidx + 16] = hb1;
      if (Hf) { Hf[gidx] = hh[0]; Hf[gidx + 16] = hh[1]; }
    }
    __syncthreads();   // h_{t+1} buffer complete before next step reads it
  }
}

// ---------------- contrastive loss + alpha ----------------
// grid (127, 8); block 256 = 4 waves; wave handles 8 batch rows serially.
__global__ __launch_bounds__(256) void loss_k(
    const float* __restrict__ WC, const float* __restrict__ P,
    const int* __restrict__ neg, float* __restrict__ alpha, float* __restrict__ loss)
{
  const int t = blockIdx.x;                       // 0..126
  const int w = threadIdx.x >> 6, lane = threadIdx.x & 63;
  __shared__ float wls[4];
  float lsum = 0.f;
#pragma unroll 1
  for (int bi = 0; bi < 8; ++bi) {
    const int b = blockIdx.y * 32 + w * 8 + bi;
    const float4 wc4 = *(const float4*)&WC[(size_t)(b * TDIM + t) * DDIM + lane * 4];
    float s[16];
    {
      const float4 p4 = *(const float4*)&P[(size_t)(b * TDIM + t + 1) * DDIM + lane * 4];
      s[0] = wc4.x * p4.x + wc4.y * p4.y + wc4.z * p4.z + wc4.w * p4.w;
    }
#pragma unroll
    for (int n = 0; n < 15; ++n) {
      const int rb = neg[(t * 15 + n) * 256 + b];
      const float4 p4 = *(const float4*)&P[(size_t)(rb * TDIM + t + 1) * DDIM + lane * 4];
      s[n + 1] = wc4.x * p4.x + wc4.y * p4.y + wc4.z * p4.z + wc4.w * p4.w;
    }
#pragma unroll
    for (int n = 0; n < 16; ++n) {
      float v = s[n];
#pragma unroll
      for (int off = 32; off > 0; off >>= 1) v += __shfl_xor(v, off);
      s[n] = v * (1.f / 256.f);                   // mean over D
    }
    float mx = s[0];
#pragma unroll
    for (int n = 1; n < 16; ++n) mx = fmaxf(mx, s[n]);
    float se = 0.f;
#pragma unroll
    for (int n = 0; n < 16; ++n) se += __expf(s[n] - mx);
    lsum -= (s[0] - mx - __logf(se));             // -pos_ce
    if (t == TDIM - 2 && lane == 0) alpha[b] = s[0];   // alpha == sp[:,126]
  }
  if (lane == 0) wls[w] = lsum;
  __syncthreads();
  if (threadIdx.x == 0)
    atomicAdd(loss, (wls[0] + wls[1] + wls[2] + wls[3]) * (1.f / 256.f));
}

// ---------------- y = gelu(H[:,-1]@Wp1^T) @ Wp2^T (second half) ----------------
__global__ __launch_bounds__(256) void y_k(const float* __restrict__ Yh,
                                           const float* __restrict__ Wp2,
                                           float* __restrict__ y) {
  const int w = threadIdx.x >> 6, lane = threadIdx.x & 63;
  const int b = blockIdx.x * 4 + w;
  const float4 a = *(const float4*)&Yh[(size_t)b * 256 + lane * 4];
  const float4 q = *(const float4*)&Wp2[lane * 4];
  float s = a.x * q.x + a.y * q.y + a.z * q.z + a.w * q.w;
#pragma unroll
  for (int off = 32; off > 0; off >>= 1) s += __shfl_xor(s, off);
  if (lane == 0) y[b] = s;
}

// ---------------- launch ----------------
extern "C" void kernel_launch(void* const* d_in, const int* in_sizes, int n_in,
                              void* d_out, int out_size, void* d_ws, size_t ws_size,
                              hipStream_t stream) {
  (void)in_sizes; (void)n_in; (void)out_size; (void)ws_size;
  const float* P    = (const float*)d_in[0];
  const float* bih0 = (const float*)d_in[3];
  const float* bhh0 = (const float*)d_in[4];
  const float* bih1 = (const float*)d_in[7];
  const float* bhh1 = (const float*)d_in[8];

  char* ws = (char*)d_ws;
  float*          gi   = (float*)(ws + 0);                       // 100663296 B
  unsigned short* Xbf  = (unsigned short*)(ws + 100663296);      // 16777216 B (H1bf then Hbf)
  unsigned short* Pbf  = (unsigned short*)(ws + 117440512);      // 16777216 B (Pbf then G1bf)
  float*          WC   = (float*)(ws + 134217728);               // 33554432 B
  unsigned short* wb   = (unsigned short*)(ws + 167772160);      // 2097152 B of bf16 weights
  unsigned short* wih0b = wb;
  unsigned short* whh0b = wb + 196608;
  unsigned short* wih1b = wb + 393216;
  unsigned short* whh1b = wb + 589824;
  unsigned short* wbW   = wb + 786432;
  unsigned short* wp1b  = wb + 851968;
  unsigned short* wr1b  = wb + 917504;
  unsigned short* wr2b  = wb + 983040;
  float*          Yh   = (float*)(ws + 169869312);               // 262144 B

  // n-gate weight repacks live in the WC region (WC is written only AFTER both gru_rec)
  unsigned short* wnp0 = (unsigned short*)WC;            // 131072 B
  unsigned short* wnp1 = wnp0 + 65536;                   // 131072 B

  float* out  = (float*)d_out;
  float* Hout = out;                  // 8388608
  float* Yout = out + 8388608;        // 256
  float* Rout = out + 8388864;        // 8388608
  float* Aout = out + 16777472;       // 256
  float* Lout = out + 16777728;       // 1

  cvt_bf16<<<8192, 256, 0, stream>>>(P, Pbf, 2097152);
  cvt_bf16<<<192, 256, 0, stream>>>((const float*)d_in[1], wih0b, 49152);
  cvt_bf16<<<192, 256, 0, stream>>>((const float*)d_in[2], whh0b, 49152);
  cvt_bf16<<<192, 256, 0, stream>>>((const float*)d_in[5], wih1b, 49152);
  cvt_bf16<<<192, 256, 0, stream>>>((const float*)d_in[6], whh1b, 49152);
  cvt_bf16<<<64, 256, 0, stream>>>((const float*)d_in[9],  wbW,  16384);
  cvt_bf16<<<64, 256, 0, stream>>>((const float*)d_in[10], wp1b, 16384);
  cvt_bf16<<<64, 256, 0, stream>>>((const float*)d_in[12], wr1b, 16384);
  cvt_bf16<<<64, 256, 0, stream>>>((const float*)d_in[13], wr2b, 16384);
  wn_pack<<<32, 256, 0, stream>>>(whh0b, wnp0);
  wn_pack<<<32, 256, 0, stream>>>(whh1b, wnp1);

  dim3 thr(256);
  // gi0 = Pbf @ Wih0^T + bih0
  gemm_bf16<<<dim3(6, 256), thr, 0, stream>>>(Pbf, 256, wih0b, 256, bih0, gi, nullptr, 256, 768, 0);
  // layer 0 recurrence -> H1bf
  gru_rec<<<16, 512, 0, stream>>>(gi, whh0b, wnp0, bhh0, nullptr, Xbf);
  // gi1 = H1bf @ Wih1^T + bih1
  gemm_bf16<<<dim3(6, 256), thr, 0, stream>>>(Xbf, 256, wih1b, 256, bih1, gi, nullptr, 256, 768, 0);
  // layer 1 recurrence -> H (fp32 out) + Hbf
  gru_rec<<<16, 512, 0, stream>>>(gi, whh1b, wnp1, bhh1, Hout, Xbf);
  // WCfull = H @ W^T
  gemm_bf16<<<dim3(2, 256), thr, 0, stream>>>(Xbf, 256, wbW, 256, nullptr, WC, nullptr, 256, 256, 0);
  // G1 = gelu(H @ Wr1^T) (bf16 only, reuse Pbf)
  gemm_bf16<<<dim3(2, 256), thr, 0, stream>>>(Xbf, 256, wr1b, 256, nullptr, nullptr, Pbf, 256, 256, 1);
  // R = G1 @ Wr2^T
  gemm_bf16<<<dim3(2, 256), thr, 0, stream>>>(Pbf, 256, wr2b, 256, nullptr, Rout, nullptr, 256, 256, 0);
  // Yh = gelu(H[:,127,:] @ Wp1^T)  (A rows strided by T*HID)
  gemm_bf16<<<dim3(2, 2), thr, 0, stream>>>(Xbf + 127 * 256, 32768, wp1b, 256, nullptr, Yh, nullptr, 256, 256, 1);
  y_k<<<64, 256, 0, stream>>>(Yh, (const float*)d_in[11], Yout);

  hipMemsetAsync(Lout, 0, 4, stream);
  loss_k<<<dim3(127, 8), thr, 0, stream>>>(WC, P, (const int*)d_in[14], Aout, Lout);
}